// Round 3
// baseline (1374.623 us; speedup 1.0000x reference)
//
#include <hip/hip_runtime.h>
#include <math.h>

typedef unsigned short u16;
typedef u16 u16x8 __attribute__((ext_vector_type(8)));
typedef __bf16 bf16x8 __attribute__((ext_vector_type(8)));
typedef float f32x4 __attribute__((ext_vector_type(4)));

#define MBL (1LL << 20)

__device__ __forceinline__ u16 f2bf(float x) {
    unsigned u = __float_as_uint(x);
    return (u16)((u + 0x7fffu + ((u >> 16) & 1u)) >> 16);
}
__device__ __forceinline__ float bf2f(u16 h) { return __uint_as_float(((unsigned)h) << 16); }
__device__ __forceinline__ float silu_f(float x) { return x / (1.f + __expf(-x)); }

// ---------------------------------------------------------------------------
// Split-fp32 MFMA GEMM, fp32 in / fp32 out.  C = alpha*(A @ B^T) + bias [+op].
// A [M,K] fp32 row-major, B [N,K] fp32 row-major (always NT).
// In-register split to bf16 hi/lo during LDS staging; 3 MFMA per K-slice
// (hh + hl + lh), dropped lo*lo term ~2^-18 rel.
// EPI: 0 = store, 1 = silu then store, 2 = add addp then store.
// z: bh = zbase+z; zb = bh>>1 (batch), zh = bh&1 (head) strides + pure-z strides.
// ---------------------------------------------------------------------------
template<int EPI>
__global__ __launch_bounds__(256)
void gemm_sp(const float* __restrict__ Af, const float* __restrict__ Bf,
             float* __restrict__ Cf,
             long lda, long ldb, long ldc, int K, float alpha,
             const float* __restrict__ bias,
             const float* __restrict__ addp, long ldadd,
             int zbase,
             long sAb, long sAh2, long sAz,
             long sBb, long sBh2, long sBz,
             long sCb, long sCh2, long sCz)
{
    const int z = blockIdx.z, bh = zbase + z, zb = bh >> 1, zh = bh & 1;
    Af += (long)zb * sAb + (long)zh * sAh2 + (long)z * sAz;
    Bf += (long)zb * sBb + (long)zh * sBh2 + (long)z * sBz;
    Cf += (long)zb * sCb + (long)zh * sCh2 + (long)z * sCz;

    __shared__ u16 As[2][128 * 32];   // [hi/lo][row*32 + k]
    __shared__ u16 Bs[2][128 * 32];

    const int tid = threadIdx.x;
    const int wave = tid >> 6, lane = tid & 63;
    const long m0 = (long)blockIdx.y * 128;
    const long n0 = (long)blockIdx.x * 128;

    // staging: thread -> (row = tid>>1, k-half = (tid&1)*16), 16 fp32 each of A,B
    const int srow = tid >> 1;
    const int sh   = (tid & 1) << 4;
    const float* gA = Af + (m0 + srow) * lda + sh;
    const float* gB = Bf + (n0 + srow) * ldb + sh;
    const int sBase = srow * 32 + sh;

    const int wr = (wave >> 1) << 6;   // wave row offset
    const int wc = (wave & 1) << 6;    // wave col offset
    const int fr = lane & 15;
    const int fk = (lane >> 4) << 3;

    f32x4 acc[4][4];
#pragma unroll
    for (int i = 0; i < 4; ++i)
#pragma unroll
        for (int j = 0; j < 4; ++j) acc[i][j] = (f32x4)0.f;

    for (int kb = 0; kb < K; kb += 32) {
        float a[16], b[16];
        *(float4*)&a[0]  = *(const float4*)(gA + kb);
        *(float4*)&a[4]  = *(const float4*)(gA + kb + 4);
        *(float4*)&a[8]  = *(const float4*)(gA + kb + 8);
        *(float4*)&a[12] = *(const float4*)(gA + kb + 12);
        *(float4*)&b[0]  = *(const float4*)(gB + kb);
        *(float4*)&b[4]  = *(const float4*)(gB + kb + 4);
        *(float4*)&b[8]  = *(const float4*)(gB + kb + 8);
        *(float4*)&b[12] = *(const float4*)(gB + kb + 12);
        u16 ahv[16], alv[16], bhv[16], blv[16];
#pragma unroll
        for (int u = 0; u < 16; ++u) {
            u16 h = f2bf(a[u]); ahv[u] = h; alv[u] = f2bf(a[u] - bf2f(h));
            u16 g = f2bf(b[u]); bhv[u] = g; blv[u] = f2bf(b[u] - bf2f(g));
        }
        __syncthreads();   // prior iteration's LDS reads complete
        *(u16x8*)&As[0][sBase]     = *(u16x8*)&ahv[0];
        *(u16x8*)&As[0][sBase + 8] = *(u16x8*)&ahv[8];
        *(u16x8*)&As[1][sBase]     = *(u16x8*)&alv[0];
        *(u16x8*)&As[1][sBase + 8] = *(u16x8*)&alv[8];
        *(u16x8*)&Bs[0][sBase]     = *(u16x8*)&bhv[0];
        *(u16x8*)&Bs[0][sBase + 8] = *(u16x8*)&bhv[8];
        *(u16x8*)&Bs[1][sBase]     = *(u16x8*)&blv[0];
        *(u16x8*)&Bs[1][sBase + 8] = *(u16x8*)&blv[8];
        __syncthreads();

        bf16x8 ah[4], al[4], bh8[4], bl8[4];
#pragma unroll
        for (int i = 0; i < 4; ++i) {
            const int r = (wr + (i << 4) + fr) * 32 + fk;
            ah[i] = *(const bf16x8*)&As[0][r];
            al[i] = *(const bf16x8*)&As[1][r];
        }
#pragma unroll
        for (int j = 0; j < 4; ++j) {
            const int r = (wc + (j << 4) + fr) * 32 + fk;
            bh8[j] = *(const bf16x8*)&Bs[0][r];
            bl8[j] = *(const bf16x8*)&Bs[1][r];
        }
#pragma unroll
        for (int i = 0; i < 4; ++i)
#pragma unroll
            for (int j = 0; j < 4; ++j) {
                acc[i][j] = __builtin_amdgcn_mfma_f32_16x16x32_bf16(ah[i], bh8[j], acc[i][j], 0, 0, 0);
                acc[i][j] = __builtin_amdgcn_mfma_f32_16x16x32_bf16(ah[i], bl8[j], acc[i][j], 0, 0, 0);
                acc[i][j] = __builtin_amdgcn_mfma_f32_16x16x32_bf16(al[i], bh8[j], acc[i][j], 0, 0, 0);
            }
    }

    const int rl = (lane >> 4) << 2;
#pragma unroll
    for (int j = 0; j < 4; ++j) {
        const long col = n0 + wc + (j << 4) + fr;
        const float bb = bias ? bias[col] : 0.f;
#pragma unroll
        for (int i = 0; i < 4; ++i) {
#pragma unroll
            for (int r2 = 0; r2 < 4; ++r2) {
                const long row = m0 + wr + (i << 4) + rl + r2;
                float c = acc[i][j][r2] * alpha + bb;
                if (EPI == 1) c = silu_f(c);
                if (EPI == 2) c += addp[row * ldadd + col];
                Cf[row * ldc + col] = c;
            }
        }
    }
}

// v group [ib][2048][1024] fp32 -> vt [ib*2+h][512(d)][2048(s)] fp32
__global__ __launch_bounds__(256)
void transpose_vf(const float* __restrict__ v, float* __restrict__ vt)
{
    const int z = blockIdx.z;           // ib*2 + h
    const int ib = z >> 1, h = z & 1;
    const float* src = v + (long)ib * 2097152 + (long)h * 512;
    float* dst = vt + (long)z * 1048576;
    __shared__ float T[64][68];
    const int t = threadIdx.x;
    const int r = t >> 2, c0 = (t & 3) << 4;
    const long sBase = (long)blockIdx.x * 64;   // s
    const long dBase = (long)blockIdx.y * 64;   // d
    const float* sp = src + (sBase + r) * 1024 + dBase + c0;
#pragma unroll
    for (int q = 0; q < 4; ++q)
        *(float4*)&T[r][c0 + 4 * q] = *(const float4*)(sp + 4 * q);
    __syncthreads();
    float* dp = dst + (dBase + r) * 2048 + sBase + c0;
#pragma unroll
    for (int q = 0; q < 4; ++q) {
        float4 o;
        o.x = T[c0 + 4 * q + 0][r]; o.y = T[c0 + 4 * q + 1][r];
        o.z = T[c0 + 4 * q + 2][r]; o.w = T[c0 + 4 * q + 3][r];
        *(float4*)(dp + 4 * q) = o;
    }
}

// in-place row softmax, rows of 2048; 1 wave/row, 4 rows/block
__global__ __launch_bounds__(256)
void softmax_rows(float* __restrict__ P)
{
    const int lane = threadIdx.x & 63;
    const long row = ((long)blockIdx.x << 2) + (threadIdx.x >> 6);
    float* pr = P + row * 2048;
    float4 xv[8];
#pragma unroll
    for (int i = 0; i < 8; ++i) xv[i] = *(const float4*)(pr + (lane << 2) + (i << 8));
    float m = -3.4e38f;
#pragma unroll
    for (int i = 0; i < 8; ++i)
        m = fmaxf(m, fmaxf(fmaxf(xv[i].x, xv[i].y), fmaxf(xv[i].z, xv[i].w)));
#pragma unroll
    for (int off = 32; off >= 1; off >>= 1) m = fmaxf(m, __shfl_xor(m, off));
    float s = 0.f;
#pragma unroll
    for (int i = 0; i < 8; ++i) {
        xv[i].x = __expf(xv[i].x - m); xv[i].y = __expf(xv[i].y - m);
        xv[i].z = __expf(xv[i].z - m); xv[i].w = __expf(xv[i].w - m);
        s += xv[i].x + xv[i].y + xv[i].z + xv[i].w;
    }
#pragma unroll
    for (int off = 32; off >= 1; off >>= 1) s += __shfl_xor(s, off);
    const float r = 1.f / s;
#pragma unroll
    for (int i = 0; i < 8; ++i) {
        xv[i].x *= r; xv[i].y *= r; xv[i].z *= r; xv[i].w *= r;
        *(float4*)(pr + (lane << 2) + (i << 8)) = xv[i];
    }
}

// LayerNorm rows of 512; 1 wave/row, 4 rows/block
__global__ __launch_bounds__(256)
void layernorm_rows(const float* __restrict__ h,
                    const float* __restrict__ gamma,
                    const float* __restrict__ beta,
                    float* __restrict__ o)
{
    const int lane = threadIdx.x & 63;
    const long row = ((long)blockIdx.x << 2) + (threadIdx.x >> 6);
    const float* hr = h + row * 512;
    float v[8];
    *(float4*)&v[0] = *(const float4*)(hr + (lane << 3));
    *(float4*)&v[4] = *(const float4*)(hr + (lane << 3) + 4);
    float s = 0.f;
#pragma unroll
    for (int i = 0; i < 8; ++i) s += v[i];
#pragma unroll
    for (int off = 32; off >= 1; off >>= 1) s += __shfl_xor(s, off);
    const float mu = s * (1.f / 512.f);
    float sq = 0.f;
#pragma unroll
    for (int i = 0; i < 8; ++i) { v[i] -= mu; sq = fmaf(v[i], v[i], sq); }
#pragma unroll
    for (int off = 32; off >= 1; off >>= 1) sq += __shfl_xor(sq, off);
    const float rs = rsqrtf(sq * (1.f / 512.f) + 1e-5f);
    float g[8], b[8];
    *(float4*)&g[0] = *(const float4*)(gamma + (lane << 3));
    *(float4*)&g[4] = *(const float4*)(gamma + (lane << 3) + 4);
    *(float4*)&b[0] = *(const float4*)(beta + (lane << 3));
    *(float4*)&b[4] = *(const float4*)(beta + (lane << 3) + 4);
    float ov[8];
#pragma unroll
    for (int i = 0; i < 8; ++i) ov[i] = fmaf(v[i] * rs, g[i], b[i]);
    float* orow = o + row * 512;
    *(float4*)(orow + (lane << 3))     = *(float4*)&ov[0];
    *(float4*)(orow + (lane << 3) + 4) = *(float4*)&ov[4];
}

extern "C" void kernel_launch(void* const* d_in, const int* in_sizes, int n_in,
                              void* d_out, int out_size, void* d_ws, size_t ws_size,
                              hipStream_t stream)
{
    const float* x    = (const float*)d_in[0];
    const float* skip = (const float*)d_in[1];
    const float* Wq   = (const float*)d_in[2];
    const float* bq   = (const float*)d_in[3];
    const float* Wk   = (const float*)d_in[4];
    const float* bk   = (const float*)d_in[5];
    const float* Wv   = (const float*)d_in[6];
    const float* bv   = (const float*)d_in[7];
    const float* Wo   = (const float*)d_in[8];
    const float* bo   = (const float*)d_in[9];
    const float* Wl   = (const float*)d_in[10];
    const float* bl   = (const float*)d_in[11];
    const float* gm   = (const float*)d_in[12];
    const float* bt   = (const float*)d_in[13];
    const float* Wp   = (const float*)d_in[14];
    const float* bp   = (const float*)d_in[15];
    float* out = (float*)d_out;

    // adaptive batch-group size: each group of gb batches needs gb*64 MB
    long gbl = (long)(ws_size / (64 * MBL));
    int gb = gbl < 1 ? 1 : (gbl > 8 ? 8 : (int)gbl);

    float* ws  = (float*)d_ws;
    const long G = gb;
    float* qb  = ws;                       // gb * 2M floats
    float* kb_ = ws + G * 2097152;         // gb * 2M
    float* vb  = ws + 2 * G * 2097152;     // gb * 2M  (attO after transpose)
    float* vtb = ws + 3 * G * 2097152;     // gb * 2M  (lnh later)
    float* scb = ws + 4 * G * 2097152;     // gb * 8M  (scores, both heads)
    float* oproj = qb;                     // gb * 1M (q dead after scores)
    float* hb    = kb_;                    // gb * 1M (k dead after scores)
    float* lnh   = vtb;                    // gb * 1M (vt dead after PV)

    const float sscale = 0.044194173824159216f;  // 1/sqrt(512)
    const long Z = 0;

    for (int b0 = 0; b0 < 8; b0 += gb) {
        const int gc = (8 - b0) < gb ? (8 - b0) : gb;
        // ---- QKV projections: [gc*2048,512] @ W[1024,512]^T ----
        gemm_sp<0><<<dim3(8, gc * 16, 1), 256, 0, stream>>>(
            x + (long)b0 * 1048576, Wq, qb, 512, 512, 1024, 512, 1.f, bq,
            nullptr, 0, 0, Z,Z,Z, Z,Z,Z, Z,Z,Z);
        gemm_sp<0><<<dim3(8, gc * 16, 1), 256, 0, stream>>>(
            x + (long)b0 * 1048576, Wk, kb_, 512, 512, 1024, 512, 1.f, bk,
            nullptr, 0, 0, Z,Z,Z, Z,Z,Z, Z,Z,Z);
        gemm_sp<0><<<dim3(8, gc * 16, 1), 256, 0, stream>>>(
            x + (long)b0 * 1048576, Wv, vb, 512, 512, 1024, 512, 1.f, bv,
            nullptr, 0, 0, Z,Z,Z, Z,Z,Z, Z,Z,Z);
        // ---- v -> vt ----
        transpose_vf<<<dim3(32, 8, 2 * gc), 256, 0, stream>>>(vb, vtb);
        // ---- scores = q @ k^T / sqrt(512) ----
        gemm_sp<0><<<dim3(16, 16, 2 * gc), 256, 0, stream>>>(
            qb - (long)b0 * 2097152, kb_ - (long)b0 * 2097152, scb,
            1024, 1024, 2048, 512, sscale, nullptr, nullptr, 0, 2 * b0,
            2097152L, 512, Z, 2097152L, 512, Z, Z, Z, 4194304L);
        // ---- softmax in place ----
        softmax_rows<<<dim3(gc * 1024), 256, 0, stream>>>(scb);
        // ---- attO = P @ vt^T (into v region) ----
        gemm_sp<0><<<dim3(4, 16, 2 * gc), 256, 0, stream>>>(
            scb, vtb, vb - (long)b0 * 2097152,
            2048, 2048, 1024, 2048, 1.f, nullptr, nullptr, 0, 2 * b0,
            Z, Z, 4194304L, Z, Z, 1048576L, 2097152L, 512, Z);
        // ---- oproj = silu(attO @ Wo^T + bo) ----
        gemm_sp<1><<<dim3(4, gc * 16, 1), 256, 0, stream>>>(
            vb, Wo, oproj, 1024, 1024, 512, 1024, 1.f, bo,
            nullptr, 0, 0, Z,Z,Z, Z,Z,Z, Z,Z,Z);
        // ---- h = oproj @ Wl^T + bl ----
        gemm_sp<0><<<dim3(4, gc * 16, 1), 256, 0, stream>>>(
            oproj, Wl, hb, 512, 512, 512, 512, 1.f, bl,
            nullptr, 0, 0, Z,Z,Z, Z,Z,Z, Z,Z,Z);
        // ---- LayerNorm ----
        layernorm_rows<<<dim3(gc * 512), 256, 0, stream>>>(hb, gm, bt, lnh);
        // ---- out = lnh + skip @ Wp^T + bp ----
        gemm_sp<2><<<dim3(4, gc * 16, 1), 256, 0, stream>>>(
            skip + (long)b0 * 1048576, Wp, out + (long)b0 * 1048576,
            512, 512, 512, 512, 1.f, bp, lnh, 512, 0, Z,Z,Z, Z,Z,Z, Z,Z,Z);
    }
}